// Round 5
// baseline (226.363 us; speedup 1.0000x reference)
//
#include <hip/hip_runtime.h>

// HolomorphicHealingBackprop — closed form + 4-deep explicit load batching.
// (R4 was an infra failure — "container failed twice" — this is an
// unchanged resubmit of the R3-proposed kernel to get a clean measurement.)
//
// Math (verified R3, absmax 2^-8 unchanged): df = 4.0 everywhere,
// a = tanh(4), C = (1-a)/a. Both normalizes scale-invariant and
// q(x)conj(q) = |q|^2 e0 collapse the whole op to:
//     out = normalize( (w + C*|q|^2, x, y, z) )
//
// R3 post-mortem: closed form was a NULL -> kernel is latency-bound on
// reads, not VALU-bound. Flat 1-elem/thread holds only ~1 KB/wave in
// flight (~18 KB/CU at 57% occupancy) vs the ~17 KB/CU needed at copy
// BW. Fix: 4 quats/thread, block-strided (each load instruction fully
// coalesced), all 4 loads issued into NAMED regs before any compute
// (R1 failed because a loop let the compiler recycle regs: VGPR=24,
// ~1 load in flight). 4 KB/wave in flight -> 4x latency-hiding headroom.

#define C_TA 6.7115040148e-4f  // (1 - tanh(4)) / tanh(4)

typedef float f32x4 __attribute__((ext_vector_type(4)));

__device__ __forceinline__ f32x4 heal_one(f32x4 q) {
  // q = (w, x, y, z) in lanes 0..3
  float S = q.x * q.x + q.y * q.y + q.z * q.z + q.w * q.w;
  float pw = __builtin_fmaf(C_TA, S, q.x);  // w + C*S

  float d = pw * pw + q.y * q.y + q.z * q.z + q.w * q.w;
  float inv = __builtin_amdgcn_rsqf(d);     // v_rsq_f32

  f32x4 r;
  r.x = pw * inv;
  r.y = q.y * inv;
  r.z = q.z * inv;
  r.w = q.w * inv;
  return r;
}

__global__ __launch_bounds__(256) void heal_kernel(
    const f32x4* __restrict__ xin, f32x4* __restrict__ out, int n_quat) {
  const int base = blockIdx.x * 1024 + threadIdx.x;

  if (base + 768 < n_quat) {
    // Fast path: 4 independent loads in flight before any compute.
    f32x4 q0 = xin[base];
    f32x4 q1 = xin[base + 256];
    f32x4 q2 = xin[base + 512];
    f32x4 q3 = xin[base + 768];

    f32x4 r0 = heal_one(q0);
    f32x4 r1 = heal_one(q1);
    f32x4 r2 = heal_one(q2);
    f32x4 r3 = heal_one(q3);

    out[base]       = r0;
    out[base + 256] = r1;
    out[base + 512] = r2;
    out[base + 768] = r3;
  } else {
    // Tail block (exact-divide at bench shape: never taken).
    for (int k = 0; k < 4; ++k) {
      int i = base + k * 256;
      if (i < n_quat) out[i] = heal_one(xin[i]);
    }
  }
}

extern "C" void kernel_launch(void* const* d_in, const int* in_sizes, int n_in,
                              void* d_out, int out_size, void* d_ws, size_t ws_size,
                              hipStream_t stream) {
  const f32x4* x = (const f32x4*)d_in[0];
  f32x4* out = (f32x4*)d_out;
  int n_quat = in_sizes[0] / 4;  // 8,388,608 quaternions

  const int block = 256;
  const int per_block = block * 4;  // 1024 quats per block
  int grid = (n_quat + per_block - 1) / per_block;  // 8192 blocks
  heal_kernel<<<grid, block, 0, stream>>>(x, out, n_quat);
}

// Round 6
// 222.543 us; speedup vs baseline: 1.0172x; 1.0172x over previous
//
#include <hip/hip_runtime.h>

// HolomorphicHealingBackprop — closed form, flat 1-elem/thread (best
// measured structure, R0/R3), NON-TEMPORAL stores as the single new lever.
//
// Math (verified since R3, absmax 2^-8 unchanged): df = 4.0 everywhere,
// a = tanh(4), C = (1-a)/a; both normalizes are scale-invariant and
// q(x)conj(q) = |q|^2 e0, so:  out = normalize( (w + C*|q|^2, x, y, z) )
//
// Ledger of refuted levers (all null-to-negative vs flat 1-elem):
//   R1 capped grid-stride     -> latency-bound regression (VALUBusy 23%)
//   R2 split-half + NT stores -> -6 us (confounded structure)
//   R3 closed-form math       -> null (kernel never VALU-co-limited)
//   R5 4-deep named load batch-> null (not MLP-limited either)
// Remaining mechanism: R1 counters showed FETCH = 67 MB = HALF the input,
// i.e. L3 serves half the reads and our own output's write-allocation
// evicts the rest. NT stores (no L3 allocation) -> input fully resident
// -> FETCH ~0, physical HBM ~= write stream only.

#define C_TA 6.7115040148e-4f  // (1 - tanh(4)) / tanh(4)

typedef float f32x4 __attribute__((ext_vector_type(4)));

__global__ __launch_bounds__(256) void heal_kernel(
    const f32x4* __restrict__ xin, f32x4* __restrict__ out, int n_quat) {
  int i = blockIdx.x * blockDim.x + threadIdx.x;
  if (i >= n_quat) return;

  f32x4 q = xin[i];  // (w, x, y, z) in lanes 0..3

  float S = q.x * q.x + q.y * q.y + q.z * q.z + q.w * q.w;
  float pw = __builtin_fmaf(C_TA, S, q.x);  // w + C*S

  float d = pw * pw + q.y * q.y + q.z * q.z + q.w * q.w;
  float inv = __builtin_amdgcn_rsqf(d);     // v_rsq_f32

  f32x4 r;
  r.x = pw * inv;
  r.y = q.y * inv;
  r.z = q.z * inv;
  r.w = q.w * inv;
  __builtin_nontemporal_store(r, &out[i]);
}

extern "C" void kernel_launch(void* const* d_in, const int* in_sizes, int n_in,
                              void* d_out, int out_size, void* d_ws, size_t ws_size,
                              hipStream_t stream) {
  const f32x4* x = (const f32x4*)d_in[0];
  f32x4* out = (f32x4*)d_out;
  int n_quat = in_sizes[0] / 4;  // 8,388,608 quaternions

  const int block = 256;
  int grid = (n_quat + block - 1) / block;  // 32768 blocks
  heal_kernel<<<grid, block, 0, stream>>>(x, out, n_quat);
}